// Round 11
// baseline (281.311 us; speedup 1.0000x reference)
//
#include <hip/hip_runtime.h>
#include <hip/hip_bf16.h>
#include <type_traits>

#define B_ 4
#define C_ 1024
#define T_ 2048
#define H_ 16
#define CH 64
#define NBH 64        // B_*H_
#define NTOT 8192     // B_*T_
#define SCALE 0.35355339059327373f           // 64^-0.25
#define QSCALE 0.5101340478421179f           // SCALE * log2(e): softmax in exp2 domain

typedef __attribute__((ext_vector_type(4))) float f32x4;
typedef __attribute__((ext_vector_type(8))) __bf16 bf16x8;
typedef __attribute__((ext_vector_type(4))) short short4v;
typedef __attribute__((ext_vector_type(8))) short short8v;

__device__ __forceinline__ short f2bf(float f) {
  union { __hip_bfloat16 h; short s; } u;
  u.h = __float2bfloat16(f);
  return u.s;
}

__device__ __forceinline__ unsigned cvt_pk_bf16(float lo, float hi) {
  unsigned r;
  asm("v_cvt_pk_bf16_f32 %0, %1, %2" : "=v"(r) : "v"(lo), "v"(hi));
  return r;
}

__device__ __forceinline__ void gload_lds16(const __hip_bfloat16* g, __hip_bfloat16* l) {
  __builtin_amdgcn_global_load_lds((const __attribute__((address_space(1))) void*)g,
                                   (__attribute__((address_space(3))) void*)l, 16, 0, 0);
}

// ---------------- mask dtype probe: diagonal must be all 1 under u8 interp ----------------
__global__ void detect_mask_kernel(const unsigned char* __restrict__ mb, int* __restrict__ flag) {
  __shared__ int ok;
  if (threadIdx.x == 0) ok = 1;
  __syncthreads();
  int bad = 0;
  for (int i = threadIdx.x; i < T_; i += blockDim.x)
    if (mb[(size_t)i * T_ + i] != 1) bad = 1;
  if (bad) atomicAnd(&ok, 0);
  __syncthreads();
  if (threadIdx.x == 0) *flag = ok;   // 1 => u8/bool layout, 0 => int32 layout
}

// ---------------- pack mask TRANSPOSED: bitsT[w][t] = mask[t][64w..64w+63] ----------------
__global__ __launch_bounds__(256) void mask_pack_kernel(const unsigned char* __restrict__ mu8,
    const int* __restrict__ mflag, unsigned long long* __restrict__ bitsT) {
  int idx = blockIdx.x * 256 + threadIdx.x;       // 0 .. T*32-1
  int t = idx & 2047, w = idx >> 11;
  unsigned long long v = 0;
  if (*mflag) {
    const unsigned long long* p = (const unsigned long long*)(mu8 + (size_t)t * T_ + w * 64);
    #pragma unroll
    for (int c = 0; c < 8; ++c) {
      unsigned long long by = p[c];
      #pragma unroll
      for (int j = 0; j < 8; ++j)
        v |= (unsigned long long)(((by >> (8 * j)) & 0xffULL) != 0) << (8 * c + j);
    }
  } else {
    const int* p = (const int*)mu8 + (size_t)t * T_ + w * 64;
    #pragma unroll
    for (int j = 0; j < 64; ++j)
      v |= (unsigned long long)(p[j] != 0) << j;
  }
  bitsT[(size_t)w * T_ + t] = v;
}

// ---------------- GroupNorm stats ----------------
__global__ __launch_bounds__(256) void gn_stats_kernel(const float* __restrict__ x,
                                                       float* __restrict__ stats) {
  int bg = blockIdx.x;   // b*32+g
  const float4* p = (const float4*)(x + (size_t)bg * 65536);
  float s = 0.f, s2 = 0.f;
  for (int i = threadIdx.x; i < 16384; i += 256) {
    float4 v = p[i];
    s  += v.x + v.y + v.z + v.w;
    s2 += v.x*v.x + v.y*v.y + v.z*v.z + v.w*v.w;
  }
  #pragma unroll
  for (int o = 32; o > 0; o >>= 1) { s += __shfl_down(s, o); s2 += __shfl_down(s2, o); }
  __shared__ float rs_[4], rs2_[4];
  int wave = threadIdx.x >> 6, lane = threadIdx.x & 63;
  if (lane == 0) { rs_[wave] = s; rs2_[wave] = s2; }
  __syncthreads();
  if (threadIdx.x == 0) {
    float S = rs_[0] + rs_[1] + rs_[2] + rs_[3];
    float S2 = rs2_[0] + rs2_[1] + rs2_[2] + rs2_[3];
    float mu = S * (1.f / 65536.f);
    float var = S2 * (1.f / 65536.f) - mu * mu;
    stats[2 * bg] = mu;
    stats[2 * bg + 1] = rsqrtf(var + 1e-5f);
  }
}

// ---------------- normalize + transpose: xnt[b*T+t][c] bf16 ----------------
__global__ __launch_bounds__(256) void gn_apply_t_kernel(const float* __restrict__ x,
    const float* __restrict__ stats, const float* __restrict__ gnw,
    const float* __restrict__ gnb, __hip_bfloat16* __restrict__ xnt) {
  __shared__ short sm[64 * 68];
  int n0 = blockIdx.x * 64;          // b*T + t tile
  int c0 = blockIdx.y * 64;
  int b = n0 >> 11, t0 = n0 & 2047;
  int tid = threadIdx.x;
  int c = tid >> 2;
  int tq = tid & 3;
  int cg = c0 + c;
  float mu = stats[2 * ((b << 5) + (cg >> 5))];
  float rr = stats[2 * ((b << 5) + (cg >> 5)) + 1];
  float w = gnw[cg] * rr;
  float bb = gnb[cg] - mu * w;
  const float* xp = x + (size_t)b * C_ * T_ + (size_t)cg * T_ + t0;
  #pragma unroll
  for (int jj = 0; jj < 4; ++jj) {
    int tt = tq * 16 + jj * 4;
    float4 v = *(const float4*)(xp + tt);
    short4v o4 = { f2bf(v.x * w + bb), f2bf(v.y * w + bb), f2bf(v.z * w + bb), f2bf(v.w * w + bb) };
    *(short4v*)&sm[c * 68 + tt] = o4;
  }
  __syncthreads();
  int t = tid >> 2;
  int cq = tid & 3;
  short8v a, bv;
  #pragma unroll
  for (int ii = 0; ii < 8; ++ii) {
    a[ii]  = sm[(cq * 16 + ii) * 68 + t];
    bv[ii] = sm[(cq * 16 + 8 + ii) * 68 + t];
  }
  __hip_bfloat16* dst = xnt + (size_t)(n0 + t) * C_ + c0 + cq * 16;
  *(short8v*)dst = a;
  *(short8v*)(dst + 8) = bv;
}

// ---------------- f32 -> bf16 convert (weights) ----------------
__global__ void cvt_kernel(const float* __restrict__ s, __hip_bfloat16* __restrict__ d, int n4) {
  int i = blockIdx.x * 256 + threadIdx.x;
  if (i >= n4) return;
  float4 v = ((const float4*)s)[i];
  short4v o = { f2bf(v.x), f2bf(v.y), f2bf(v.z), f2bf(v.w) };
  *(short4v*)(d + (size_t)i * 4) = o;
}

// ---------------- GEMM  C[m][n] = sum_k A[m][k]*Bt[n][k]  (R9 pipelined 128^2) ----------
// Triple-buffered LDS (48KB), one raw s_barrier per K-step, counted vmcnt (4 steady/0 last).
// R11: n-MAJOR per-XCD chunking — each XCD owns 8 consecutive n-panels (2MB, L2-resident,
// reused by all m-tiles); B fetched from HBM once total instead of 3x/XCD (m-major was
// 384MB of L3/HBM B-traffic).
template<int EPI>
__global__ __launch_bounds__(256) void gemm_bt_kernel(
    const __hip_bfloat16* __restrict__ A, const __hip_bfloat16* __restrict__ Bt,
    const float* __restrict__ bias,
    __hip_bfloat16* __restrict__ qo, __hip_bfloat16* __restrict__ ko,
    __hip_bfloat16* __restrict__ vto,
    const float* __restrict__ x, const float* __restrict__ stats,
    const float* __restrict__ gnw, const float* __restrict__ gnb,
    float* __restrict__ out, int K, int mtiles) {
  __shared__ __hip_bfloat16 As[3][128 * 32];
  __shared__ __hip_bfloat16 Bs[3][128 * 32];
  const int nwg = gridDim.x;
  const int cpx = nwg >> 3;
  const int flat = (blockIdx.x & 7) * cpx + (blockIdx.x >> 3);
  const int m0 = (flat % mtiles) * 128, n0 = (flat / mtiles) * 128;   // n-major
  const int tid = threadIdx.x, wave = tid >> 6, lane = tid & 63;
  const int wr = wave >> 1, wc = wave & 1;
  const int l15 = lane & 15, l4 = lane >> 4;
  const int lr = lane >> 2, lc8 = (lane & 3) * 8;
  const __hip_bfloat16* ga = A + (size_t)(m0 + wave * 32 + lr) * K + lc8;
  const __hip_bfloat16* gb = Bt + (size_t)(n0 + wave * 32 + lr) * K + lc8;
  const int ldst = (wave * 32) * 32;
  f32x4 zero = {0.f, 0.f, 0.f, 0.f};
  f32x4 acc[4][4];
  #pragma unroll
  for (int mi = 0; mi < 4; ++mi)
    #pragma unroll
    for (int ni = 0; ni < 4; ++ni) acc[mi][ni] = zero;

  const int nit = K >> 5;
  gload_lds16(ga, &As[0][ldst]);
  gload_lds16(ga + (size_t)16 * K, &As[0][ldst + 16 * 32]);
  gload_lds16(gb, &Bs[0][ldst]);
  gload_lds16(gb + (size_t)16 * K, &Bs[0][ldst + 16 * 32]);
  gload_lds16(ga + 32, &As[1][ldst]);
  gload_lds16(ga + 32 + (size_t)16 * K, &As[1][ldst + 16 * 32]);
  gload_lds16(gb + 32, &Bs[1][ldst]);
  gload_lds16(gb + 32 + (size_t)16 * K, &Bs[1][ldst + 16 * 32]);

  int cur = 0, nb = 2;
  for (int it = 0; it < nit; ++it) {
    if (it + 1 < nit) asm volatile("s_waitcnt vmcnt(4)" ::: "memory");
    else              asm volatile("s_waitcnt vmcnt(0)" ::: "memory");
    __builtin_amdgcn_s_barrier();
    __builtin_amdgcn_sched_barrier(0);
    if (it + 2 < nit) {
      const int kt = (it + 2) * 32;
      gload_lds16(ga + kt, &As[nb][ldst]);
      gload_lds16(ga + kt + (size_t)16 * K, &As[nb][ldst + 16 * 32]);
      gload_lds16(gb + kt, &Bs[nb][ldst]);
      gload_lds16(gb + kt + (size_t)16 * K, &Bs[nb][ldst + 16 * 32]);
    }
    bf16x8 af[4], bf[4];
    #pragma unroll
    for (int mi = 0; mi < 4; ++mi)
      af[mi] = *(const bf16x8*)&As[cur][(wr * 64 + mi * 16 + l15) * 32 + l4 * 8];
    #pragma unroll
    for (int ni = 0; ni < 4; ++ni)
      bf[ni] = *(const bf16x8*)&Bs[cur][(wc * 64 + ni * 16 + l15) * 32 + l4 * 8];
    #pragma unroll
    for (int mi = 0; mi < 4; ++mi)
      #pragma unroll
      for (int ni = 0; ni < 4; ++ni)
        acc[mi][ni] = __builtin_amdgcn_mfma_f32_16x16x32_bf16(af[mi], bf[ni], acc[mi][ni], 0, 0, 0);
    nb = cur;
    cur = (cur == 2) ? 0 : cur + 1;
  }

  const int bb = n0 >> 11;
  if constexpr (EPI == 0) {
    #pragma unroll
    for (int mi = 0; mi < 4; ++mi) {
      int ob = m0 + wr * 64 + mi * 16 + (l4 << 2);
      int h = ob / 192, o2 = ob % 192;
      int bh = (bb << 4) + h;
      float b4[4];
      #pragma unroll
      for (int r = 0; r < 4; ++r) b4[r] = bias[ob + r];
      #pragma unroll
      for (int ni = 0; ni < 4; ++ni) {
        int n = n0 + wc * 64 + ni * 16 + l15;
        int t = n & 2047;
        f32x4 v = acc[mi][ni];
        if (o2 < 64) {
          short4v pk = { f2bf((v[0]+b4[0])*QSCALE), f2bf((v[1]+b4[1])*QSCALE),
                         f2bf((v[2]+b4[2])*QSCALE), f2bf((v[3]+b4[3])*QSCALE) };
          *(short4v*)(qo + ((size_t)bh * T_ + t) * CH + o2) = pk;
        } else if (o2 < 128) {
          short4v pk = { f2bf((v[0]+b4[0])*SCALE), f2bf((v[1]+b4[1])*SCALE),
                         f2bf((v[2]+b4[2])*SCALE), f2bf((v[3]+b4[3])*SCALE) };
          *(short4v*)(ko + ((size_t)bh * T_ + t) * CH + (o2 - 64)) = pk;
        } else {
          // V^T store with key-permutation within each 32-t block:
          // sigma(16u+4a+s) = 8a+4u+s, so attn's PV B-operand is the raw S regs.
          int p = t & 31;
          int tp = (t & ~31) | (((p >> 2) & 3) * 8 + ((p >> 4) & 1) * 4 + (p & 3));
          #pragma unroll
          for (int r = 0; r < 4; ++r)
            vto[((size_t)bh * CH + (o2 - 128 + r)) * T_ + tp] = __float2bfloat16(v[r] + b4[r]);
        }
      }
    }
  } else {
    #pragma unroll
    for (int mi = 0; mi < 4; ++mi) {
      int ob = m0 + wr * 64 + mi * 16 + (l4 << 2);
      float w4[4], c4[4], bp4[4];
      #pragma unroll
      for (int r = 0; r < 4; ++r) {
        int o = ob + r;
        float mu = stats[2 * ((bb << 5) + (o >> 5))];
        float rr = stats[2 * ((bb << 5) + (o >> 5)) + 1];
        w4[r] = gnw[o] * rr;
        c4[r] = gnb[o] - mu * w4[r];
        bp4[r] = bias[o];
      }
      #pragma unroll
      for (int ni = 0; ni < 4; ++ni) {
        int n = n0 + wc * 64 + ni * 16 + l15;
        int t = n & 2047;
        f32x4 v = acc[mi][ni];
        #pragma unroll
        for (int r = 0; r < 4; ++r) {
          int o = ob + r;
          size_t xi = (size_t)bb * C_ * T_ + (size_t)o * T_ + t;
          float xn = x[xi] * w4[r] + c4[r];
          out[xi] = xn + v[r] + bp4[r];
        }
      }
    }
  }
}

// ---------------- flash attention v9: ring-4 buffers, compile-time phase unroll ----------
// 512 blocks x 256 thr (the L2-sharing dispatch shape). 4 waves x 64 q/wave. Same verified
// schedule as R8/R9 (distance-2 prefetch, vmcnt 12 steady / 8 last), but the 32 iters run
// as 8 x 4 phases with buffer index a compile-time constant -> every ds_read / stage LDS
// address is an immediate (kills the ~50 VALU cndmask-per-iter of runtime KV[cur%3]).
__global__ __launch_bounds__(256) void attn_kernel(
    const __hip_bfloat16* __restrict__ q, const __hip_bfloat16* __restrict__ k,
    const __hip_bfloat16* __restrict__ vt, const unsigned long long* __restrict__ mbitsT,
    __hip_bfloat16* __restrict__ at) {
  const int bid = blockIdx.x;
  const int bh = (bid & 7) * 8 + ((bid >> 3) & 7);   // XCD-contiguous bh groups
  const int qt = bid >> 6;
  const int b = bh >> 4, h = bh & 15;
  const int lane = threadIdx.x & 63, wave = threadIdx.x >> 6;
  const int l15 = lane & 15, l4 = lane >> 4;
  const int qw0 = qt * 256 + wave * 64;
  const float NINF = -__builtin_inff();

  __shared__ __hip_bfloat16 KV[8][4096];   // [0..3]=K ring, [4..7]=V^T ring (64 KB)

  const __hip_bfloat16* kb = k + (size_t)bh * T_ * CH;
  const __hip_bfloat16* vb = vt + (size_t)bh * CH * T_;

  bf16x8 qa[4][2];
  #pragma unroll
  for (int j = 0; j < 4; ++j) {
    const __hip_bfloat16* qp = q + ((size_t)bh * T_ + qw0 + j * 16 + l15) * CH + l4 * 8;
    qa[j][0] = *(const bf16x8*)qp;
    qa[j][1] = *(const bf16x8*)(qp + 32);
  }

  union { unsigned u[4]; bf16x8 v; } ones;
  ones.u[0] = ones.u[1] = ones.u[2] = ones.u[3] = 0x3F803F80u;

  const int sidx0 = (wave * 2) * 64 + lane;
  const int sidx1 = (wave * 2 + 1) * 64 + lane;
  const int skey0 = sidx0 >> 3, sp0 = sidx0 & 7;
  const int skey1 = sidx1 >> 3, sp1 = sidx1 & 7;
  const int kc0 = (sp0 ^ (skey0 & 7)) * 8, kc1 = (sp1 ^ (skey1 & 7)) * 8;

  f32x4 zero = {0.f, 0.f, 0.f, 0.f};
  f32x4 O[4][4];
  f32x4 lacc[4];
  #pragma unroll
  for (int j = 0; j < 4; ++j) {
    lacc[j] = zero;
    #pragma unroll
    for (int ci = 0; ci < 4; ++ci) O[j][ci] = zero;
  }

  // prologue: masks(0) + stage tiles 0,1; full drain once
  unsigned long long mcur[4], mnext[4];
  #pragma unroll
  for (int j = 0; j < 4; ++j) { mcur[j] = mbitsT[(size_t)qw0 + j * 16 + l15]; mnext[j] = mcur[j]; }
  gload_lds16(kb + (size_t)skey0 * CH + kc0, &KV[0][(wave * 2) * 512]);
  gload_lds16(kb + (size_t)skey1 * CH + kc1, &KV[0][(wave * 2 + 1) * 512]);
  gload_lds16(vb + (size_t)skey0 * T_ + kc0, &KV[4][(wave * 2) * 512]);
  gload_lds16(vb + (size_t)skey1 * T_ + kc1, &KV[4][(wave * 2 + 1) * 512]);
  gload_lds16(kb + (size_t)(64 + skey0) * CH + kc0, &KV[1][(wave * 2) * 512]);
  gload_lds16(kb + (size_t)(64 + skey1) * CH + kc1, &KV[1][(wave * 2 + 1) * 512]);
  gload_lds16(vb + (size_t)skey0 * T_ + 64 + kc0, &KV[5][(wave * 2) * 512]);
  gload_lds16(vb + (size_t)skey1 * T_ + 64 + kc1, &KV[5][(wave * 2 + 1) * 512]);
  asm volatile("s_waitcnt vmcnt(0)" ::: "memory");

  auto phase = [&](auto Cc, int itb) {
    constexpr int C = decltype(Cc)::value;          // buffer = compile-time constant
    constexpr int NB = (C + 2) & 3;
    const int it = itb + C;
    if (it < 31) asm volatile("s_waitcnt vmcnt(12)" ::: "memory");
    else         asm volatile("s_waitcnt vmcnt(8)" ::: "memory");
    __builtin_amdgcn_s_barrier();                   // tile it ready; buf C's prior read done
    __builtin_amdgcn_sched_barrier(0);
    if (it < 30) {                                  // stage tile it+2 into ring slot NB
      const int s_next = (it + 2) * 64;
      gload_lds16(kb + (size_t)(s_next + skey0) * CH + kc0, &KV[NB][(wave * 2) * 512]);
      gload_lds16(kb + (size_t)(s_next + skey1) * CH + kc1, &KV[NB][(wave * 2 + 1) * 512]);
      gload_lds16(vb + (size_t)skey0 * T_ + s_next + kc0, &KV[4 + NB][(wave * 2) * 512]);
      gload_lds16(vb + (size_t)skey1 * T_ + s_next + kc1, &KV[4 + NB][(wave * 2 + 1) * 512]);
    }
    if (it < 31) {
      const int s_next = (it + 1) * 64;
      #pragma unroll
      for (int j = 0; j < 4; ++j)
        mnext[j] = mbitsT[(size_t)(s_next >> 6) * T_ + qw0 + j * 16 + l15];
    }

    bf16x8 kf[4][2], vf[2][4];
    #pragma unroll
    for (int ni = 0; ni < 4; ++ni) {
      int row = ni * 16 + l15;
      kf[ni][0] = *(const bf16x8*)&KV[C][row * 64 + ((l4 ^ (row & 7)) << 3)];
      kf[ni][1] = *(const bf16x8*)&KV[C][row * 64 + (((4 + l4) ^ (row & 7)) << 3)];
    }
    #pragma unroll
    for (int j2 = 0; j2 < 2; ++j2)
      #pragma unroll
      for (int ci = 0; ci < 4; ++ci) {
        int row = ci * 16 + l15;
        vf[j2][ci] = *(const bf16x8*)&KV[4 + C][row * 64 + (((j2 * 4 + l4) ^ (row & 7)) << 3)];
      }

    #pragma unroll
    for (int j = 0; j < 4; ++j) {
      f32x4 S[4];
      __builtin_amdgcn_s_setprio(1);
      #pragma unroll
      for (int ni = 0; ni < 4; ++ni) {
        f32x4 z = __builtin_amdgcn_mfma_f32_16x16x32_bf16(kf[ni][0], qa[j][0], zero, 0, 0, 0);
        S[ni] = __builtin_amdgcn_mfma_f32_16x16x32_bf16(kf[ni][1], qa[j][1], z, 0, 0, 0);
      }
      __builtin_amdgcn_s_setprio(0);
      unsigned long long mb = mcur[j];
      unsigned w0 = (unsigned)(mb >> (l4 * 4));
      unsigned w1 = (unsigned)(mb >> (l4 * 4 + 32));
      #pragma unroll
      for (int ni = 0; ni < 4; ++ni)
        #pragma unroll
        for (int r = 0; r < 4; ++r) {
          unsigned bit = ((ni < 2 ? (w0 >> (16 * ni + r)) : (w1 >> (16 * (ni - 2) + r))) & 1u);
          S[ni][r] = __builtin_amdgcn_exp2f(fminf(bit ? S[ni][r] : NINF, 24.f));
        }
      union { unsigned u[4]; bf16x8 v; } pf0, pf1;
      pf0.u[0] = cvt_pk_bf16(S[0][0], S[0][1]);
      pf0.u[1] = cvt_pk_bf16(S[0][2], S[0][3]);
      pf0.u[2] = cvt_pk_bf16(S[1][0], S[1][1]);
      pf0.u[3] = cvt_pk_bf16(S[1][2], S[1][3]);
      pf1.u[0] = cvt_pk_bf16(S[2][0], S[2][1]);
      pf1.u[1] = cvt_pk_bf16(S[2][2], S[2][3]);
      pf1.u[2] = cvt_pk_bf16(S[3][0], S[3][1]);
      pf1.u[3] = cvt_pk_bf16(S[3][2], S[3][3]);
      __builtin_amdgcn_s_setprio(1);
      lacc[j] = __builtin_amdgcn_mfma_f32_16x16x32_bf16(ones.v, pf0.v, lacc[j], 0, 0, 0);
      #pragma unroll
      for (int ci = 0; ci < 4; ++ci)
        O[j][ci] = __builtin_amdgcn_mfma_f32_16x16x32_bf16(vf[0][ci], pf0.v, O[j][ci], 0, 0, 0);
      lacc[j] = __builtin_amdgcn_mfma_f32_16x16x32_bf16(ones.v, pf1.v, lacc[j], 0, 0, 0);
      #pragma unroll
      for (int ci = 0; ci < 4; ++ci)
        O[j][ci] = __builtin_amdgcn_mfma_f32_16x16x32_bf16(vf[1][ci], pf1.v, O[j][ci], 0, 0, 0);
      __builtin_amdgcn_s_setprio(0);
      mcur[j] = mnext[j];
    }
  };

  for (int itb = 0; itb < 32; itb += 4) {
    phase(std::integral_constant<int, 0>{}, itb);
    phase(std::integral_constant<int, 1>{}, itb);
    phase(std::integral_constant<int, 2>{}, itb);
    phase(std::integral_constant<int, 3>{}, itb);
  }

  // epilogue: O/l -> wave-private LDS stripe (transpose) -> coalesced b128 stores
  __builtin_amdgcn_s_barrier();
  asm volatile("s_waitcnt vmcnt(0)" ::: "memory");
  __hip_bfloat16* scr = &KV[wave][0];
  #pragma unroll
  for (int j = 0; j < 4; ++j) {
    float invl = 1.f / lacc[j][0];                  // q = l15 lane-local
    int prow = j * 16 + l15;
    #pragma unroll
    for (int ci = 0; ci < 4; ++ci)
      #pragma unroll
      for (int pp = 0; pp < 2; ++pp) {
        int ch = ci * 16 + l4 * 4 + pp * 2;
        int chunk = ch >> 3, wi = ch & 7;
        unsigned pk = cvt_pk_bf16(O[j][ci][pp * 2] * invl, O[j][ci][pp * 2 + 1] * invl);
        *(unsigned*)&scr[prow * 64 + ((chunk ^ (prow & 7)) << 3) + wi] = pk;
      }
  }
  #pragma unroll
  for (int rd = 0; rd < 8; ++rd) {
    int row = rd * 8 + (lane >> 3);
    int chunk = lane & 7;
    bf16x8 ov = *(const bf16x8*)&scr[row * 64 + ((chunk ^ (row & 7)) << 3)];
    int t = qt * 256 + wave * 64 + row;
    *(bf16x8*)(at + ((size_t)b * T_ + t) * C_ + h * 64 + chunk * 8) = ov;
  }
}

extern "C" void kernel_launch(void* const* d_in, const int* in_sizes, int n_in,
                              void* d_out, int out_size, void* d_ws, size_t ws_size,
                              hipStream_t stream) {
  const float* x    = (const float*)d_in[0];
  const unsigned char* mask = (const unsigned char*)d_in[1];
  const float* gnw  = (const float*)d_in[2];
  const float* gnb  = (const float*)d_in[3];
  const float* Wqkv = (const float*)d_in[4];
  const float* bqkv = (const float*)d_in[5];
  const float* Wproj= (const float*)d_in[6];
  const float* bproj= (const float*)d_in[7];
  float* out = (float*)d_out;
  char* ws = (char*)d_ws;

  float* stats = (float*)ws;                                   // 1 KB
  int* mflag   = (int*)(ws + 1024);
  unsigned long long* mbits = (unsigned long long*)(ws + 4096); // [32][2048] u64 = 512 KB
  __hip_bfloat16* xnt = (__hip_bfloat16*)(ws + 4096 + 524288);  // [8192][1024]
  __hip_bfloat16* qb  = xnt + (size_t)NTOT * C_;               // [64][2048][64]
  __hip_bfloat16* kb  = qb  + (size_t)NBH * T_ * CH;
  __hip_bfloat16* vtb = kb  + (size_t)NBH * T_ * CH;           // [64][64][2048] (key-permuted)
  __hip_bfloat16* atb = vtb + (size_t)NBH * CH * T_;           // [8192][1024]
  __hip_bfloat16* wqb = atb + (size_t)NTOT * C_;               // [3072][1024]
  __hip_bfloat16* wpb = wqb + (size_t)3 * C_ * C_;             // [1024][1024]

  detect_mask_kernel<<<1, 256, 0, stream>>>(mask, mflag);
  mask_pack_kernel<<<256, 256, 0, stream>>>(mask, mflag, mbits);
  gn_stats_kernel<<<128, 256, 0, stream>>>(x, stats);
  gn_apply_t_kernel<<<dim3(NTOT / 64, C_ / 64), 256, 0, stream>>>(x, stats, gnw, gnb, xnt);
  cvt_kernel<<<3072, 256, 0, stream>>>(Wqkv, wqb, 786432);
  cvt_kernel<<<1024, 256, 0, stream>>>(Wproj, wpb, 262144);
  gemm_bt_kernel<0><<<1536, 256, 0, stream>>>(wqb, xnt, bqkv, qb, kb, vtb,
      nullptr, nullptr, nullptr, nullptr, nullptr, C_, 24);
  attn_kernel<<<512, 256, 0, stream>>>(qb, kb, vtb, mbits, atb);
  gemm_bt_kernel<1><<<512, 256, 0, stream>>>(wpb, atb, bproj,
      nullptr, nullptr, nullptr, x, stats, gnw, gnb, out, C_, 8);
}

// Round 12
// 261.030 us; speedup vs baseline: 1.0777x; 1.0777x over previous
//
#include <hip/hip_runtime.h>
#include <hip/hip_bf16.h>

#define B_ 4
#define C_ 1024
#define T_ 2048
#define H_ 16
#define CH 64
#define NBH 64        // B_*H_
#define NTOT 8192     // B_*T_
#define SCALE 0.35355339059327373f           // 64^-0.25
#define QSCALE 0.5101340478421179f           // SCALE * log2(e): softmax in exp2 domain

typedef __attribute__((ext_vector_type(4))) float f32x4;
typedef __attribute__((ext_vector_type(8))) __bf16 bf16x8;
typedef __attribute__((ext_vector_type(4))) short short4v;
typedef __attribute__((ext_vector_type(8))) short short8v;

__device__ __forceinline__ short f2bf(float f) {
  union { __hip_bfloat16 h; short s; } u;
  u.h = __float2bfloat16(f);
  return u.s;
}

__device__ __forceinline__ unsigned cvt_pk_bf16(float lo, float hi) {
  unsigned r;
  asm("v_cvt_pk_bf16_f32 %0, %1, %2" : "=v"(r) : "v"(lo), "v"(hi));
  return r;
}

__device__ __forceinline__ void gload_lds16(const __hip_bfloat16* g, __hip_bfloat16* l) {
  __builtin_amdgcn_global_load_lds((const __attribute__((address_space(1))) void*)g,
                                   (__attribute__((address_space(3))) void*)l, 16, 0, 0);
}

// ---------------- mask dtype probe: diagonal must be all 1 under u8 interp ----------------
__global__ void detect_mask_kernel(const unsigned char* __restrict__ mb, int* __restrict__ flag) {
  __shared__ int ok;
  if (threadIdx.x == 0) ok = 1;
  __syncthreads();
  int bad = 0;
  for (int i = threadIdx.x; i < T_; i += blockDim.x)
    if (mb[(size_t)i * T_ + i] != 1) bad = 1;
  if (bad) atomicAnd(&ok, 0);
  __syncthreads();
  if (threadIdx.x == 0) *flag = ok;   // 1 => u8/bool layout, 0 => int32 layout
}

// ---------------- pack mask TRANSPOSED: bitsT[w][t] = mask[t][64w..64w+63] ----------------
__global__ __launch_bounds__(256) void mask_pack_kernel(const unsigned char* __restrict__ mu8,
    const int* __restrict__ mflag, unsigned long long* __restrict__ bitsT) {
  int idx = blockIdx.x * 256 + threadIdx.x;       // 0 .. T*32-1
  int t = idx & 2047, w = idx >> 11;
  unsigned long long v = 0;
  if (*mflag) {
    const unsigned long long* p = (const unsigned long long*)(mu8 + (size_t)t * T_ + w * 64);
    #pragma unroll
    for (int c = 0; c < 8; ++c) {
      unsigned long long by = p[c];
      #pragma unroll
      for (int j = 0; j < 8; ++j)
        v |= (unsigned long long)(((by >> (8 * j)) & 0xffULL) != 0) << (8 * c + j);
    }
  } else {
    const int* p = (const int*)mu8 + (size_t)t * T_ + w * 64;
    #pragma unroll
    for (int j = 0; j < 64; ++j)
      v |= (unsigned long long)(p[j] != 0) << j;
  }
  bitsT[(size_t)w * T_ + t] = v;
}

// ---------------- GroupNorm stats ----------------
__global__ __launch_bounds__(256) void gn_stats_kernel(const float* __restrict__ x,
                                                       float* __restrict__ stats) {
  int bg = blockIdx.x;   // b*32+g
  const float4* p = (const float4*)(x + (size_t)bg * 65536);
  float s = 0.f, s2 = 0.f;
  for (int i = threadIdx.x; i < 16384; i += 256) {
    float4 v = p[i];
    s  += v.x + v.y + v.z + v.w;
    s2 += v.x*v.x + v.y*v.y + v.z*v.z + v.w*v.w;
  }
  #pragma unroll
  for (int o = 32; o > 0; o >>= 1) { s += __shfl_down(s, o); s2 += __shfl_down(s2, o); }
  __shared__ float rs_[4], rs2_[4];
  int wave = threadIdx.x >> 6, lane = threadIdx.x & 63;
  if (lane == 0) { rs_[wave] = s; rs2_[wave] = s2; }
  __syncthreads();
  if (threadIdx.x == 0) {
    float S = rs_[0] + rs_[1] + rs_[2] + rs_[3];
    float S2 = rs2_[0] + rs2_[1] + rs2_[2] + rs2_[3];
    float mu = S * (1.f / 65536.f);
    float var = S2 * (1.f / 65536.f) - mu * mu;
    stats[2 * bg] = mu;
    stats[2 * bg + 1] = rsqrtf(var + 1e-5f);
  }
}

// ---------------- normalize + transpose: xnt[b*T+t][c] bf16 ----------------
__global__ __launch_bounds__(256) void gn_apply_t_kernel(const float* __restrict__ x,
    const float* __restrict__ stats, const float* __restrict__ gnw,
    const float* __restrict__ gnb, __hip_bfloat16* __restrict__ xnt) {
  __shared__ short sm[64 * 68];
  int n0 = blockIdx.x * 64;          // b*T + t tile
  int c0 = blockIdx.y * 64;
  int b = n0 >> 11, t0 = n0 & 2047;
  int tid = threadIdx.x;
  int c = tid >> 2;
  int tq = tid & 3;
  int cg = c0 + c;
  float mu = stats[2 * ((b << 5) + (cg >> 5))];
  float rr = stats[2 * ((b << 5) + (cg >> 5)) + 1];
  float w = gnw[cg] * rr;
  float bb = gnb[cg] - mu * w;
  const float* xp = x + (size_t)b * C_ * T_ + (size_t)cg * T_ + t0;
  #pragma unroll
  for (int jj = 0; jj < 4; ++jj) {
    int tt = tq * 16 + jj * 4;
    float4 v = *(const float4*)(xp + tt);
    short4v o4 = { f2bf(v.x * w + bb), f2bf(v.y * w + bb), f2bf(v.z * w + bb), f2bf(v.w * w + bb) };
    *(short4v*)&sm[c * 68 + tt] = o4;
  }
  __syncthreads();
  int t = tid >> 2;
  int cq = tid & 3;
  short8v a, bv;
  #pragma unroll
  for (int ii = 0; ii < 8; ++ii) {
    a[ii]  = sm[(cq * 16 + ii) * 68 + t];
    bv[ii] = sm[(cq * 16 + 8 + ii) * 68 + t];
  }
  __hip_bfloat16* dst = xnt + (size_t)(n0 + t) * C_ + c0 + cq * 16;
  *(short8v*)dst = a;
  *(short8v*)(dst + 8) = bv;
}

// ---------------- f32 -> bf16 convert (weights) ----------------
__global__ void cvt_kernel(const float* __restrict__ s, __hip_bfloat16* __restrict__ d, int n4) {
  int i = blockIdx.x * 256 + threadIdx.x;
  if (i >= n4) return;
  float4 v = ((const float4*)s)[i];
  short4v o = { f2bf(v.x), f2bf(v.y), f2bf(v.z), f2bf(v.w) };
  *(short4v*)(d + (size_t)i * 4) = o;
}

// ---------------- GEMM  C[m][n] = sum_k A[m][k]*Bt[n][k]  (R9 pipelined 128^2) ----------
// Triple-buffered LDS (48KB), one raw s_barrier per K-step, counted vmcnt (4 steady/0 last).
// n-MAJOR per-XCD chunking (R11, kept): each XCD owns consecutive n-panels (L2-resident,
// reused across all m-tiles) -> B fetched from HBM ~once total.
template<int EPI>
__global__ __launch_bounds__(256) void gemm_bt_kernel(
    const __hip_bfloat16* __restrict__ A, const __hip_bfloat16* __restrict__ Bt,
    const float* __restrict__ bias,
    __hip_bfloat16* __restrict__ qo, __hip_bfloat16* __restrict__ ko,
    __hip_bfloat16* __restrict__ vto,
    const float* __restrict__ x, const float* __restrict__ stats,
    const float* __restrict__ gnw, const float* __restrict__ gnb,
    float* __restrict__ out, int K, int mtiles) {
  __shared__ __hip_bfloat16 As[3][128 * 32];
  __shared__ __hip_bfloat16 Bs[3][128 * 32];
  const int nwg = gridDim.x;
  const int cpx = nwg >> 3;
  const int flat = (blockIdx.x & 7) * cpx + (blockIdx.x >> 3);
  const int m0 = (flat % mtiles) * 128, n0 = (flat / mtiles) * 128;   // n-major
  const int tid = threadIdx.x, wave = tid >> 6, lane = tid & 63;
  const int wr = wave >> 1, wc = wave & 1;
  const int l15 = lane & 15, l4 = lane >> 4;
  const int lr = lane >> 2, lc8 = (lane & 3) * 8;
  const __hip_bfloat16* ga = A + (size_t)(m0 + wave * 32 + lr) * K + lc8;
  const __hip_bfloat16* gb = Bt + (size_t)(n0 + wave * 32 + lr) * K + lc8;
  const int ldst = (wave * 32) * 32;
  f32x4 zero = {0.f, 0.f, 0.f, 0.f};
  f32x4 acc[4][4];
  #pragma unroll
  for (int mi = 0; mi < 4; ++mi)
    #pragma unroll
    for (int ni = 0; ni < 4; ++ni) acc[mi][ni] = zero;

  const int nit = K >> 5;
  gload_lds16(ga, &As[0][ldst]);
  gload_lds16(ga + (size_t)16 * K, &As[0][ldst + 16 * 32]);
  gload_lds16(gb, &Bs[0][ldst]);
  gload_lds16(gb + (size_t)16 * K, &Bs[0][ldst + 16 * 32]);
  gload_lds16(ga + 32, &As[1][ldst]);
  gload_lds16(ga + 32 + (size_t)16 * K, &As[1][ldst + 16 * 32]);
  gload_lds16(gb + 32, &Bs[1][ldst]);
  gload_lds16(gb + 32 + (size_t)16 * K, &Bs[1][ldst + 16 * 32]);

  int cur = 0, nb = 2;
  for (int it = 0; it < nit; ++it) {
    if (it + 1 < nit) asm volatile("s_waitcnt vmcnt(4)" ::: "memory");
    else              asm volatile("s_waitcnt vmcnt(0)" ::: "memory");
    __builtin_amdgcn_s_barrier();
    __builtin_amdgcn_sched_barrier(0);
    if (it + 2 < nit) {
      const int kt = (it + 2) * 32;
      gload_lds16(ga + kt, &As[nb][ldst]);
      gload_lds16(ga + kt + (size_t)16 * K, &As[nb][ldst + 16 * 32]);
      gload_lds16(gb + kt, &Bs[nb][ldst]);
      gload_lds16(gb + kt + (size_t)16 * K, &Bs[nb][ldst + 16 * 32]);
    }
    bf16x8 af[4], bf[4];
    #pragma unroll
    for (int mi = 0; mi < 4; ++mi)
      af[mi] = *(const bf16x8*)&As[cur][(wr * 64 + mi * 16 + l15) * 32 + l4 * 8];
    #pragma unroll
    for (int ni = 0; ni < 4; ++ni)
      bf[ni] = *(const bf16x8*)&Bs[cur][(wc * 64 + ni * 16 + l15) * 32 + l4 * 8];
    #pragma unroll
    for (int mi = 0; mi < 4; ++mi)
      #pragma unroll
      for (int ni = 0; ni < 4; ++ni)
        acc[mi][ni] = __builtin_amdgcn_mfma_f32_16x16x32_bf16(af[mi], bf[ni], acc[mi][ni], 0, 0, 0);
    nb = cur;
    cur = (cur == 2) ? 0 : cur + 1;
  }

  const int bb = n0 >> 11;
  if constexpr (EPI == 0) {
    #pragma unroll
    for (int mi = 0; mi < 4; ++mi) {
      int ob = m0 + wr * 64 + mi * 16 + (l4 << 2);
      int h = ob / 192, o2 = ob % 192;
      int bh = (bb << 4) + h;
      float b4[4];
      #pragma unroll
      for (int r = 0; r < 4; ++r) b4[r] = bias[ob + r];
      #pragma unroll
      for (int ni = 0; ni < 4; ++ni) {
        int n = n0 + wc * 64 + ni * 16 + l15;
        int t = n & 2047;
        f32x4 v = acc[mi][ni];
        if (o2 < 64) {
          short4v pk = { f2bf((v[0]+b4[0])*QSCALE), f2bf((v[1]+b4[1])*QSCALE),
                         f2bf((v[2]+b4[2])*QSCALE), f2bf((v[3]+b4[3])*QSCALE) };
          *(short4v*)(qo + ((size_t)bh * T_ + t) * CH + o2) = pk;
        } else if (o2 < 128) {
          short4v pk = { f2bf((v[0]+b4[0])*SCALE), f2bf((v[1]+b4[1])*SCALE),
                         f2bf((v[2]+b4[2])*SCALE), f2bf((v[3]+b4[3])*SCALE) };
          *(short4v*)(ko + ((size_t)bh * T_ + t) * CH + (o2 - 64)) = pk;
        } else {
          // V^T store with key-permutation within each 32-t block:
          // sigma(16u+4a+s) = 8a+4u+s, so attn's PV B-operand is the raw S regs.
          int p = t & 31;
          int tp = (t & ~31) | (((p >> 2) & 3) * 8 + ((p >> 4) & 1) * 4 + (p & 3));
          #pragma unroll
          for (int r = 0; r < 4; ++r)
            vto[((size_t)bh * CH + (o2 - 128 + r)) * T_ + tp] = __float2bfloat16(v[r] + b4[r]);
        }
      }
    }
  } else {
    #pragma unroll
    for (int mi = 0; mi < 4; ++mi) {
      int ob = m0 + wr * 64 + mi * 16 + (l4 << 2);
      float w4[4], c4[4], bp4[4];
      #pragma unroll
      for (int r = 0; r < 4; ++r) {
        int o = ob + r;
        float mu = stats[2 * ((bb << 5) + (o >> 5))];
        float rr = stats[2 * ((bb << 5) + (o >> 5)) + 1];
        w4[r] = gnw[o] * rr;
        c4[r] = gnb[o] - mu * w4[r];
        bp4[r] = bias[o];
      }
      #pragma unroll
      for (int ni = 0; ni < 4; ++ni) {
        int n = n0 + wc * 64 + ni * 16 + l15;
        int t = n & 2047;
        f32x4 v = acc[mi][ni];
        #pragma unroll
        for (int r = 0; r < 4; ++r) {
          int o = ob + r;
          size_t xi = (size_t)bb * C_ * T_ + (size_t)o * T_ + t;
          float xn = x[xi] * w4[r] + c4[r];
          out[xi] = xn + v[r] + bp4[r];
        }
      }
    }
  }
}

// ---------------- flash attention v8.1 (R9-verified: 48KB triple-buffer, 122us) ----------
// 512 blocks x 256 thr (the L2-sharing dispatch shape; 3 blocks/CU). 4 waves x 64 q/wave.
// K,V^T triple-buffered (48KB); stage(it+2) after the single barrier; steady vmcnt(12);
// final iter vmcnt(8). S^T=mfma(K,Q); P=exp2(min(S,24)); permuted V -> PV B-frag = lane's
// own packed S regs; l = ones-MFMA column sum.
__global__ __launch_bounds__(256) void attn_kernel(
    const __hip_bfloat16* __restrict__ q, const __hip_bfloat16* __restrict__ k,
    const __hip_bfloat16* __restrict__ vt, const unsigned long long* __restrict__ mbitsT,
    __hip_bfloat16* __restrict__ at) {
  const int bid = blockIdx.x;
  const int bh = (bid & 7) * 8 + ((bid >> 3) & 7);
  const int qt = bid >> 6;
  const int b = bh >> 4, h = bh & 15;
  const int lane = threadIdx.x & 63, wave = threadIdx.x >> 6;
  const int l15 = lane & 15, l4 = lane >> 4;
  const int qw0 = qt * 256 + wave * 64;
  const float NINF = -__builtin_inff();

  __shared__ __hip_bfloat16 KV[6][4096];

  const __hip_bfloat16* kb = k + (size_t)bh * T_ * CH;
  const __hip_bfloat16* vb = vt + (size_t)bh * CH * T_;

  bf16x8 qa[4][2];
  #pragma unroll
  for (int j = 0; j < 4; ++j) {
    const __hip_bfloat16* qp = q + ((size_t)bh * T_ + qw0 + j * 16 + l15) * CH + l4 * 8;
    qa[j][0] = *(const bf16x8*)qp;
    qa[j][1] = *(const bf16x8*)(qp + 32);
  }

  union { unsigned u[4]; bf16x8 v; } ones;
  ones.u[0] = ones.u[1] = ones.u[2] = ones.u[3] = 0x3F803F80u;

  const int sidx0 = (wave * 2) * 64 + lane;
  const int sidx1 = (wave * 2 + 1) * 64 + lane;
  const int skey0 = sidx0 >> 3, sp0 = sidx0 & 7;
  const int skey1 = sidx1 >> 3, sp1 = sidx1 & 7;
  const int kc0 = (sp0 ^ (skey0 & 7)) * 8, kc1 = (sp1 ^ (skey1 & 7)) * 8;

  f32x4 zero = {0.f, 0.f, 0.f, 0.f};
  f32x4 O[4][4];
  f32x4 lacc[4];
  #pragma unroll
  for (int j = 0; j < 4; ++j) {
    lacc[j] = zero;
    #pragma unroll
    for (int ci = 0; ci < 4; ++ci) O[j][ci] = zero;
  }

  unsigned long long mcur[4], mnext[4];
  #pragma unroll
  for (int j = 0; j < 4; ++j) { mcur[j] = mbitsT[(size_t)qw0 + j * 16 + l15]; mnext[j] = mcur[j]; }
  gload_lds16(kb + (size_t)skey0 * CH + kc0, &KV[0][(wave * 2) * 512]);
  gload_lds16(kb + (size_t)skey1 * CH + kc1, &KV[0][(wave * 2 + 1) * 512]);
  gload_lds16(vb + (size_t)skey0 * T_ + kc0, &KV[3][(wave * 2) * 512]);
  gload_lds16(vb + (size_t)skey1 * T_ + kc1, &KV[3][(wave * 2 + 1) * 512]);
  gload_lds16(kb + (size_t)(64 + skey0) * CH + kc0, &KV[1][(wave * 2) * 512]);
  gload_lds16(kb + (size_t)(64 + skey1) * CH + kc1, &KV[1][(wave * 2 + 1) * 512]);
  gload_lds16(vb + (size_t)skey0 * T_ + 64 + kc0, &KV[4][(wave * 2) * 512]);
  gload_lds16(vb + (size_t)skey1 * T_ + 64 + kc1, &KV[4][(wave * 2 + 1) * 512]);
  asm volatile("s_waitcnt vmcnt(0)" ::: "memory");

  for (int it = 0; it < 32; ++it) {
    const int cur = it % 3;
    if (it < 31) asm volatile("s_waitcnt vmcnt(12)" ::: "memory");
    else         asm volatile("s_waitcnt vmcnt(8)" ::: "memory");
    __builtin_amdgcn_s_barrier();
    __builtin_amdgcn_sched_barrier(0);
    if (it < 30) {
      const int nb = (it + 2) % 3;
      const int s_next = (it + 2) * 64;
      gload_lds16(kb + (size_t)(s_next + skey0) * CH + kc0, &KV[nb][(wave * 2) * 512]);
      gload_lds16(kb + (size_t)(s_next + skey1) * CH + kc1, &KV[nb][(wave * 2 + 1) * 512]);
      gload_lds16(vb + (size_t)skey0 * T_ + s_next + kc0, &KV[3 + nb][(wave * 2) * 512]);
      gload_lds16(vb + (size_t)skey1 * T_ + s_next + kc1, &KV[3 + nb][(wave * 2 + 1) * 512]);
    }
    if (it < 31) {
      const int s_next = (it + 1) * 64;
      #pragma unroll
      for (int j = 0; j < 4; ++j)
        mnext[j] = mbitsT[(size_t)(s_next >> 6) * T_ + qw0 + j * 16 + l15];
    }

    bf16x8 kf[4][2], vf[2][4];
    #pragma unroll
    for (int ni = 0; ni < 4; ++ni) {
      int row = ni * 16 + l15;
      kf[ni][0] = *(const bf16x8*)&KV[cur][row * 64 + ((l4 ^ (row & 7)) << 3)];
      kf[ni][1] = *(const bf16x8*)&KV[cur][row * 64 + (((4 + l4) ^ (row & 7)) << 3)];
    }
    #pragma unroll
    for (int j2 = 0; j2 < 2; ++j2)
      #pragma unroll
      for (int ci = 0; ci < 4; ++ci) {
        int row = ci * 16 + l15;
        vf[j2][ci] = *(const bf16x8*)&KV[3 + cur][row * 64 + (((j2 * 4 + l4) ^ (row & 7)) << 3)];
      }

    #pragma unroll
    for (int j = 0; j < 4; ++j) {
      f32x4 S[4];
      __builtin_amdgcn_s_setprio(1);
      #pragma unroll
      for (int ni = 0; ni < 4; ++ni) {
        f32x4 z = __builtin_amdgcn_mfma_f32_16x16x32_bf16(kf[ni][0], qa[j][0], zero, 0, 0, 0);
        S[ni] = __builtin_amdgcn_mfma_f32_16x16x32_bf16(kf[ni][1], qa[j][1], z, 0, 0, 0);
      }
      __builtin_amdgcn_s_setprio(0);
      unsigned long long mb = mcur[j];
      unsigned w0 = (unsigned)(mb >> (l4 * 4));
      unsigned w1 = (unsigned)(mb >> (l4 * 4 + 32));
      #pragma unroll
      for (int ni = 0; ni < 4; ++ni)
        #pragma unroll
        for (int r = 0; r < 4; ++r) {
          unsigned bit = ((ni < 2 ? (w0 >> (16 * ni + r)) : (w1 >> (16 * (ni - 2) + r))) & 1u);
          S[ni][r] = __builtin_amdgcn_exp2f(fminf(bit ? S[ni][r] : NINF, 24.f));
        }
      union { unsigned u[4]; bf16x8 v; } pf0, pf1;
      pf0.u[0] = cvt_pk_bf16(S[0][0], S[0][1]);
      pf0.u[1] = cvt_pk_bf16(S[0][2], S[0][3]);
      pf0.u[2] = cvt_pk_bf16(S[1][0], S[1][1]);
      pf0.u[3] = cvt_pk_bf16(S[1][2], S[1][3]);
      pf1.u[0] = cvt_pk_bf16(S[2][0], S[2][1]);
      pf1.u[1] = cvt_pk_bf16(S[2][2], S[2][3]);
      pf1.u[2] = cvt_pk_bf16(S[3][0], S[3][1]);
      pf1.u[3] = cvt_pk_bf16(S[3][2], S[3][3]);
      __builtin_amdgcn_s_setprio(1);
      lacc[j] = __builtin_amdgcn_mfma_f32_16x16x32_bf16(ones.v, pf0.v, lacc[j], 0, 0, 0);
      #pragma unroll
      for (int ci = 0; ci < 4; ++ci)
        O[j][ci] = __builtin_amdgcn_mfma_f32_16x16x32_bf16(vf[0][ci], pf0.v, O[j][ci], 0, 0, 0);
      lacc[j] = __builtin_amdgcn_mfma_f32_16x16x32_bf16(ones.v, pf1.v, lacc[j], 0, 0, 0);
      #pragma unroll
      for (int ci = 0; ci < 4; ++ci)
        O[j][ci] = __builtin_amdgcn_mfma_f32_16x16x32_bf16(vf[1][ci], pf1.v, O[j][ci], 0, 0, 0);
      __builtin_amdgcn_s_setprio(0);
      mcur[j] = mnext[j];
    }
  }

  __builtin_amdgcn_s_barrier();
  asm volatile("s_waitcnt vmcnt(0)" ::: "memory");
  __hip_bfloat16* scr = &KV[wave][0];
  #pragma unroll
  for (int j = 0; j < 4; ++j) {
    float invl = 1.f / lacc[j][0];
    int prow = j * 16 + l15;
    #pragma unroll
    for (int ci = 0; ci < 4; ++ci)
      #pragma unroll
      for (int pp = 0; pp < 2; ++pp) {
        int ch = ci * 16 + l4 * 4 + pp * 2;
        int chunk = ch >> 3, wi = ch & 7;
        unsigned pk = cvt_pk_bf16(O[j][ci][pp * 2] * invl, O[j][ci][pp * 2 + 1] * invl);
        *(unsigned*)&scr[prow * 64 + ((chunk ^ (prow & 7)) << 3) + wi] = pk;
      }
  }
  #pragma unroll
  for (int rd = 0; rd < 8; ++rd) {
    int row = rd * 8 + (lane >> 3);
    int chunk = lane & 7;
    bf16x8 ov = *(const bf16x8*)&scr[row * 64 + ((chunk ^ (row & 7)) << 3)];
    int t = qt * 256 + wave * 64 + row;
    *(bf16x8*)(at + ((size_t)b * T_ + t) * C_ + h * 64 + chunk * 8) = ov;
  }
}

extern "C" void kernel_launch(void* const* d_in, const int* in_sizes, int n_in,
                              void* d_out, int out_size, void* d_ws, size_t ws_size,
                              hipStream_t stream) {
  const float* x    = (const float*)d_in[0];
  const unsigned char* mask = (const unsigned char*)d_in[1];
  const float* gnw  = (const float*)d_in[2];
  const float* gnb  = (const float*)d_in[3];
  const float* Wqkv = (const float*)d_in[4];
  const float* bqkv = (const float*)d_in[5];
  const float* Wproj= (const float*)d_in[6];
  const float* bproj= (const float*)d_in[7];
  float* out = (float*)d_out;
  char* ws = (char*)d_ws;

  float* stats = (float*)ws;                                   // 1 KB
  int* mflag   = (int*)(ws + 1024);
  unsigned long long* mbits = (unsigned long long*)(ws + 4096); // [32][2048] u64 = 512 KB
  __hip_bfloat16* xnt = (__hip_bfloat16*)(ws + 4096 + 524288);  // [8192][1024]
  __hip_bfloat16* qb  = xnt + (size_t)NTOT * C_;               // [64][2048][64]
  __hip_bfloat16* kb  = qb  + (size_t)NBH * T_ * CH;
  __hip_bfloat16* vtb = kb  + (size_t)NBH * T_ * CH;           // [64][64][2048] (key-permuted)
  __hip_bfloat16* atb = vtb + (size_t)NBH * CH * T_;           // [8192][1024]
  __hip_bfloat16* wqb = atb + (size_t)NTOT * C_;               // [3072][1024]
  __hip_bfloat16* wpb = wqb + (size_t)3 * C_ * C_;             // [1024][1024]

  detect_mask_kernel<<<1, 256, 0, stream>>>(mask, mflag);
  mask_pack_kernel<<<256, 256, 0, stream>>>(mask, mflag, mbits);
  gn_stats_kernel<<<128, 256, 0, stream>>>(x, stats);
  gn_apply_t_kernel<<<dim3(NTOT / 64, C_ / 64), 256, 0, stream>>>(x, stats, gnw, gnb, xnt);
  cvt_kernel<<<3072, 256, 0, stream>>>(Wqkv, wqb, 786432);
  cvt_kernel<<<1024, 256, 0, stream>>>(Wproj, wpb, 262144);
  gemm_bt_kernel<0><<<1536, 256, 0, stream>>>(wqb, xnt, bqkv, qb, kb, vtb,
      nullptr, nullptr, nullptr, nullptr, nullptr, C_, 24);
  attn_kernel<<<512, 256, 0, stream>>>(qb, kb, vtb, mbits, atb);
  gemm_bt_kernel<1><<<512, 256, 0, stream>>>(wpb, atb, bproj,
      nullptr, nullptr, nullptr, x, stats, gnw, gnb, out, C_, 8);
}

// Round 13
// 249.584 us; speedup vs baseline: 1.1271x; 1.0459x over previous
//
#include <hip/hip_runtime.h>
#include <hip/hip_bf16.h>

#define B_ 4
#define C_ 1024
#define T_ 2048
#define H_ 16
#define CH 64
#define NBH 64        // B_*H_
#define NTOT 8192     // B_*T_
#define SCALE 0.35355339059327373f           // 64^-0.25
#define QSCALE 0.5101340478421179f           // SCALE * log2(e): softmax in exp2 domain

typedef __attribute__((ext_vector_type(4))) float f32x4;
typedef __attribute__((ext_vector_type(8))) __bf16 bf16x8;
typedef __attribute__((ext_vector_type(4))) short short4v;
typedef __attribute__((ext_vector_type(8))) short short8v;

__device__ __forceinline__ short f2bf(float f) {
  union { __hip_bfloat16 h; short s; } u;
  u.h = __float2bfloat16(f);
  return u.s;
}

__device__ __forceinline__ unsigned cvt_pk_bf16(float lo, float hi) {
  unsigned r;
  asm("v_cvt_pk_bf16_f32 %0, %1, %2" : "=v"(r) : "v"(lo), "v"(hi));
  return r;
}

__device__ __forceinline__ void gload_lds16(const __hip_bfloat16* g, __hip_bfloat16* l) {
  __builtin_amdgcn_global_load_lds((const __attribute__((address_space(1))) void*)g,
                                   (__attribute__((address_space(3))) void*)l, 16, 0, 0);
}

// ---------------- fused prep A: [0]=mask-dtype probe | [1,129)=GN stats | weight cvts ----
// All four jobs are mutually independent; branch is block-uniform.
__global__ __launch_bounds__(256) void prep_a_kernel(
    const unsigned char* __restrict__ mask, int* __restrict__ mflag,
    const float* __restrict__ x, float* __restrict__ stats,
    const float* __restrict__ Wqkv, __hip_bfloat16* __restrict__ wqb,
    const float* __restrict__ Wproj, __hip_bfloat16* __restrict__ wpb) {
  const int bid = blockIdx.x;
  if (bid == 0) {
    // mask dtype probe: diagonal must be all 1 under u8 interp
    __shared__ int ok;
    if (threadIdx.x == 0) ok = 1;
    __syncthreads();
    int bad = 0;
    for (int i = threadIdx.x; i < T_; i += blockDim.x)
      if (mask[(size_t)i * T_ + i] != 1) bad = 1;
    if (bad) atomicAnd(&ok, 0);
    __syncthreads();
    if (threadIdx.x == 0) *mflag = ok;   // 1 => u8/bool layout, 0 => int32 layout
  } else if (bid < 129) {
    // GroupNorm stats: one block per (b,g); 32ch*2048t contiguous
    int bg = bid - 1;
    const float4* p = (const float4*)(x + (size_t)bg * 65536);
    float s = 0.f, s2 = 0.f;
    for (int i = threadIdx.x; i < 16384; i += 256) {
      float4 v = p[i];
      s  += v.x + v.y + v.z + v.w;
      s2 += v.x*v.x + v.y*v.y + v.z*v.z + v.w*v.w;
    }
    #pragma unroll
    for (int o = 32; o > 0; o >>= 1) { s += __shfl_down(s, o); s2 += __shfl_down(s2, o); }
    __shared__ float rs_[4], rs2_[4];
    int wave = threadIdx.x >> 6, lane = threadIdx.x & 63;
    if (lane == 0) { rs_[wave] = s; rs2_[wave] = s2; }
    __syncthreads();
    if (threadIdx.x == 0) {
      float S = rs_[0] + rs_[1] + rs_[2] + rs_[3];
      float S2 = rs2_[0] + rs2_[1] + rs2_[2] + rs2_[3];
      float mu = S * (1.f / 65536.f);
      float var = S2 * (1.f / 65536.f) - mu * mu;
      stats[2 * bg] = mu;
      stats[2 * bg + 1] = rsqrtf(var + 1e-5f);
    }
  } else if (bid < 129 + 3072) {
    // cvt Wqkv (786432 float4 groups)
    int i = (bid - 129) * 256 + threadIdx.x;
    float4 v = ((const float4*)Wqkv)[i];
    short4v o = { f2bf(v.x), f2bf(v.y), f2bf(v.z), f2bf(v.w) };
    *(short4v*)(wqb + (size_t)i * 4) = o;
  } else {
    // cvt Wproj (262144 float4 groups)
    int i = (bid - 129 - 3072) * 256 + threadIdx.x;
    float4 v = ((const float4*)Wproj)[i];
    short4v o = { f2bf(v.x), f2bf(v.y), f2bf(v.z), f2bf(v.w) };
    *(short4v*)(wpb + (size_t)i * 4) = o;
  }
}

// ---------------- fused prep B: [0,256)=mask pack (transposed) | rest = GN apply+T -------
// pack needs mflag (prep A); apply needs stats (prep A). Branch is block-uniform.
__global__ __launch_bounds__(256) void prep_b_kernel(
    const unsigned char* __restrict__ mu8, const int* __restrict__ mflag,
    unsigned long long* __restrict__ bitsT,
    const float* __restrict__ x, const float* __restrict__ stats,
    const float* __restrict__ gnw, const float* __restrict__ gnb,
    __hip_bfloat16* __restrict__ xnt) {
  __shared__ short sm[64 * 68];
  const int bid = blockIdx.x;
  if (bid < 256) {
    // pack mask TRANSPOSED: bitsT[w][t] = mask[t][64w..64w+63]
    int idx = bid * 256 + threadIdx.x;
    int t = idx & 2047, w = idx >> 11;
    unsigned long long v = 0;
    if (*mflag) {
      const unsigned long long* p = (const unsigned long long*)(mu8 + (size_t)t * T_ + w * 64);
      #pragma unroll
      for (int c = 0; c < 8; ++c) {
        unsigned long long by = p[c];
        #pragma unroll
        for (int j = 0; j < 8; ++j)
          v |= (unsigned long long)(((by >> (8 * j)) & 0xffULL) != 0) << (8 * c + j);
      }
    } else {
      const int* p = (const int*)mu8 + (size_t)t * T_ + w * 64;
      #pragma unroll
      for (int j = 0; j < 64; ++j)
        v |= (unsigned long long)(p[j] != 0) << j;
    }
    bitsT[(size_t)w * T_ + t] = v;
  } else {
    // normalize + transpose: xnt[b*T+t][c] bf16
    int gb2 = bid - 256;                 // 0..2047
    int n0 = (gb2 & 127) * 64;           // b*T + t tile
    int c0 = (gb2 >> 7) * 64;
    int b = n0 >> 11, t0 = n0 & 2047;
    int tid = threadIdx.x;
    int c = tid >> 2;
    int tq = tid & 3;
    int cg = c0 + c;
    float mu = stats[2 * ((b << 5) + (cg >> 5))];
    float rr = stats[2 * ((b << 5) + (cg >> 5)) + 1];
    float w = gnw[cg] * rr;
    float bb = gnb[cg] - mu * w;
    const float* xp = x + (size_t)b * C_ * T_ + (size_t)cg * T_ + t0;
    #pragma unroll
    for (int jj = 0; jj < 4; ++jj) {
      int tt = tq * 16 + jj * 4;
      float4 v = *(const float4*)(xp + tt);
      short4v o4 = { f2bf(v.x * w + bb), f2bf(v.y * w + bb), f2bf(v.z * w + bb), f2bf(v.w * w + bb) };
      *(short4v*)&sm[c * 68 + tt] = o4;
    }
    __syncthreads();
    int t = tid >> 2;
    int cq = tid & 3;
    short8v a, bv;
    #pragma unroll
    for (int ii = 0; ii < 8; ++ii) {
      a[ii]  = sm[(cq * 16 + ii) * 68 + t];
      bv[ii] = sm[(cq * 16 + 8 + ii) * 68 + t];
    }
    __hip_bfloat16* dst = xnt + (size_t)(n0 + t) * C_ + c0 + cq * 16;
    *(short8v*)dst = a;
    *(short8v*)(dst + 8) = bv;
  }
}

// ---------------- GEMM  C[m][n] = sum_k A[m][k]*Bt[n][k]  (R9 pipelined 128^2) ----------
// Triple-buffered LDS (48KB), one raw s_barrier per K-step, counted vmcnt (4 steady/0 last).
// n-MAJOR per-XCD chunking: each XCD owns consecutive n-panels (L2-resident, reused across
// all m-tiles) -> B fetched from HBM ~once total.
template<int EPI>
__global__ __launch_bounds__(256) void gemm_bt_kernel(
    const __hip_bfloat16* __restrict__ A, const __hip_bfloat16* __restrict__ Bt,
    const float* __restrict__ bias,
    __hip_bfloat16* __restrict__ qo, __hip_bfloat16* __restrict__ ko,
    __hip_bfloat16* __restrict__ vto,
    const float* __restrict__ x, const float* __restrict__ stats,
    const float* __restrict__ gnw, const float* __restrict__ gnb,
    float* __restrict__ out, int K, int mtiles) {
  __shared__ __hip_bfloat16 As[3][128 * 32];
  __shared__ __hip_bfloat16 Bs[3][128 * 32];
  const int nwg = gridDim.x;
  const int cpx = nwg >> 3;
  const int flat = (blockIdx.x & 7) * cpx + (blockIdx.x >> 3);
  const int m0 = (flat % mtiles) * 128, n0 = (flat / mtiles) * 128;   // n-major
  const int tid = threadIdx.x, wave = tid >> 6, lane = tid & 63;
  const int wr = wave >> 1, wc = wave & 1;
  const int l15 = lane & 15, l4 = lane >> 4;
  const int lr = lane >> 2, lc8 = (lane & 3) * 8;
  const __hip_bfloat16* ga = A + (size_t)(m0 + wave * 32 + lr) * K + lc8;
  const __hip_bfloat16* gb = Bt + (size_t)(n0 + wave * 32 + lr) * K + lc8;
  const int ldst = (wave * 32) * 32;
  f32x4 zero = {0.f, 0.f, 0.f, 0.f};
  f32x4 acc[4][4];
  #pragma unroll
  for (int mi = 0; mi < 4; ++mi)
    #pragma unroll
    for (int ni = 0; ni < 4; ++ni) acc[mi][ni] = zero;

  const int nit = K >> 5;
  gload_lds16(ga, &As[0][ldst]);
  gload_lds16(ga + (size_t)16 * K, &As[0][ldst + 16 * 32]);
  gload_lds16(gb, &Bs[0][ldst]);
  gload_lds16(gb + (size_t)16 * K, &Bs[0][ldst + 16 * 32]);
  gload_lds16(ga + 32, &As[1][ldst]);
  gload_lds16(ga + 32 + (size_t)16 * K, &As[1][ldst + 16 * 32]);
  gload_lds16(gb + 32, &Bs[1][ldst]);
  gload_lds16(gb + 32 + (size_t)16 * K, &Bs[1][ldst + 16 * 32]);

  int cur = 0, nb = 2;
  for (int it = 0; it < nit; ++it) {
    if (it + 1 < nit) asm volatile("s_waitcnt vmcnt(4)" ::: "memory");
    else              asm volatile("s_waitcnt vmcnt(0)" ::: "memory");
    __builtin_amdgcn_s_barrier();
    __builtin_amdgcn_sched_barrier(0);
    if (it + 2 < nit) {
      const int kt = (it + 2) * 32;
      gload_lds16(ga + kt, &As[nb][ldst]);
      gload_lds16(ga + kt + (size_t)16 * K, &As[nb][ldst + 16 * 32]);
      gload_lds16(gb + kt, &Bs[nb][ldst]);
      gload_lds16(gb + kt + (size_t)16 * K, &Bs[nb][ldst + 16 * 32]);
    }
    bf16x8 af[4], bf[4];
    #pragma unroll
    for (int mi = 0; mi < 4; ++mi)
      af[mi] = *(const bf16x8*)&As[cur][(wr * 64 + mi * 16 + l15) * 32 + l4 * 8];
    #pragma unroll
    for (int ni = 0; ni < 4; ++ni)
      bf[ni] = *(const bf16x8*)&Bs[cur][(wc * 64 + ni * 16 + l15) * 32 + l4 * 8];
    #pragma unroll
    for (int mi = 0; mi < 4; ++mi)
      #pragma unroll
      for (int ni = 0; ni < 4; ++ni)
        acc[mi][ni] = __builtin_amdgcn_mfma_f32_16x16x32_bf16(af[mi], bf[ni], acc[mi][ni], 0, 0, 0);
    nb = cur;
    cur = (cur == 2) ? 0 : cur + 1;
  }

  const int bb = n0 >> 11;
  if constexpr (EPI == 0) {
    #pragma unroll
    for (int mi = 0; mi < 4; ++mi) {
      int ob = m0 + wr * 64 + mi * 16 + (l4 << 2);
      int h = ob / 192, o2 = ob % 192;
      int bh = (bb << 4) + h;
      float b4[4];
      #pragma unroll
      for (int r = 0; r < 4; ++r) b4[r] = bias[ob + r];
      #pragma unroll
      for (int ni = 0; ni < 4; ++ni) {
        int n = n0 + wc * 64 + ni * 16 + l15;
        int t = n & 2047;
        f32x4 v = acc[mi][ni];
        if (o2 < 64) {
          short4v pk = { f2bf((v[0]+b4[0])*QSCALE), f2bf((v[1]+b4[1])*QSCALE),
                         f2bf((v[2]+b4[2])*QSCALE), f2bf((v[3]+b4[3])*QSCALE) };
          *(short4v*)(qo + ((size_t)bh * T_ + t) * CH + o2) = pk;
        } else if (o2 < 128) {
          short4v pk = { f2bf((v[0]+b4[0])*SCALE), f2bf((v[1]+b4[1])*SCALE),
                         f2bf((v[2]+b4[2])*SCALE), f2bf((v[3]+b4[3])*SCALE) };
          *(short4v*)(ko + ((size_t)bh * T_ + t) * CH + (o2 - 64)) = pk;
        } else {
          // V^T store with key-permutation within each 32-t block:
          // sigma(16u+4a+s) = 8a+4u+s, so attn's PV B-operand is the raw S regs.
          int p = t & 31;
          int tp = (t & ~31) | (((p >> 2) & 3) * 8 + ((p >> 4) & 1) * 4 + (p & 3));
          #pragma unroll
          for (int r = 0; r < 4; ++r)
            vto[((size_t)bh * CH + (o2 - 128 + r)) * T_ + tp] = __float2bfloat16(v[r] + b4[r]);
        }
      }
    }
  } else {
    #pragma unroll
    for (int mi = 0; mi < 4; ++mi) {
      int ob = m0 + wr * 64 + mi * 16 + (l4 << 2);
      float w4[4], c4[4], bp4[4];
      #pragma unroll
      for (int r = 0; r < 4; ++r) {
        int o = ob + r;
        float mu = stats[2 * ((bb << 5) + (o >> 5))];
        float rr = stats[2 * ((bb << 5) + (o >> 5)) + 1];
        w4[r] = gnw[o] * rr;
        c4[r] = gnb[o] - mu * w4[r];
        bp4[r] = bias[o];
      }
      #pragma unroll
      for (int ni = 0; ni < 4; ++ni) {
        int n = n0 + wc * 64 + ni * 16 + l15;
        int t = n & 2047;
        f32x4 v = acc[mi][ni];
        #pragma unroll
        for (int r = 0; r < 4; ++r) {
          int o = ob + r;
          size_t xi = (size_t)bb * C_ * T_ + (size_t)o * T_ + t;
          float xn = x[xi] * w4[r] + c4[r];
          out[xi] = xn + v[r] + bp4[r];
        }
      }
    }
  }
}

// ---------------- flash attention v8.1 (R9-verified: 48KB triple-buffer, 122us) ----------
// 512 blocks x 256 thr (the L2-sharing dispatch shape; 3 blocks/CU capacity, 2 resident).
// 4 waves x 64 q/wave. K,V^T triple-buffered (48KB); stage(it+2) after the single barrier;
// steady vmcnt(12); final iter vmcnt(8). S^T=mfma(K,Q); P=exp2(min(S,24)); permuted V ->
// PV B-frag = lane's own packed S regs; l = ones-MFMA column sum.
__global__ __launch_bounds__(256) void attn_kernel(
    const __hip_bfloat16* __restrict__ q, const __hip_bfloat16* __restrict__ k,
    const __hip_bfloat16* __restrict__ vt, const unsigned long long* __restrict__ mbitsT,
    __hip_bfloat16* __restrict__ at) {
  const int bid = blockIdx.x;
  const int bh = (bid & 7) * 8 + ((bid >> 3) & 7);
  const int qt = bid >> 6;
  const int b = bh >> 4, h = bh & 15;
  const int lane = threadIdx.x & 63, wave = threadIdx.x >> 6;
  const int l15 = lane & 15, l4 = lane >> 4;
  const int qw0 = qt * 256 + wave * 64;
  const float NINF = -__builtin_inff();

  __shared__ __hip_bfloat16 KV[6][4096];

  const __hip_bfloat16* kb = k + (size_t)bh * T_ * CH;
  const __hip_bfloat16* vb = vt + (size_t)bh * CH * T_;

  bf16x8 qa[4][2];
  #pragma unroll
  for (int j = 0; j < 4; ++j) {
    const __hip_bfloat16* qp = q + ((size_t)bh * T_ + qw0 + j * 16 + l15) * CH + l4 * 8;
    qa[j][0] = *(const bf16x8*)qp;
    qa[j][1] = *(const bf16x8*)(qp + 32);
  }

  union { unsigned u[4]; bf16x8 v; } ones;
  ones.u[0] = ones.u[1] = ones.u[2] = ones.u[3] = 0x3F803F80u;

  const int sidx0 = (wave * 2) * 64 + lane;
  const int sidx1 = (wave * 2 + 1) * 64 + lane;
  const int skey0 = sidx0 >> 3, sp0 = sidx0 & 7;
  const int skey1 = sidx1 >> 3, sp1 = sidx1 & 7;
  const int kc0 = (sp0 ^ (skey0 & 7)) * 8, kc1 = (sp1 ^ (skey1 & 7)) * 8;

  f32x4 zero = {0.f, 0.f, 0.f, 0.f};
  f32x4 O[4][4];
  f32x4 lacc[4];
  #pragma unroll
  for (int j = 0; j < 4; ++j) {
    lacc[j] = zero;
    #pragma unroll
    for (int ci = 0; ci < 4; ++ci) O[j][ci] = zero;
  }

  unsigned long long mcur[4], mnext[4];
  #pragma unroll
  for (int j = 0; j < 4; ++j) { mcur[j] = mbitsT[(size_t)qw0 + j * 16 + l15]; mnext[j] = mcur[j]; }
  gload_lds16(kb + (size_t)skey0 * CH + kc0, &KV[0][(wave * 2) * 512]);
  gload_lds16(kb + (size_t)skey1 * CH + kc1, &KV[0][(wave * 2 + 1) * 512]);
  gload_lds16(vb + (size_t)skey0 * T_ + kc0, &KV[3][(wave * 2) * 512]);
  gload_lds16(vb + (size_t)skey1 * T_ + kc1, &KV[3][(wave * 2 + 1) * 512]);
  gload_lds16(kb + (size_t)(64 + skey0) * CH + kc0, &KV[1][(wave * 2) * 512]);
  gload_lds16(kb + (size_t)(64 + skey1) * CH + kc1, &KV[1][(wave * 2 + 1) * 512]);
  gload_lds16(vb + (size_t)skey0 * T_ + 64 + kc0, &KV[4][(wave * 2) * 512]);
  gload_lds16(vb + (size_t)skey1 * T_ + 64 + kc1, &KV[4][(wave * 2 + 1) * 512]);
  asm volatile("s_waitcnt vmcnt(0)" ::: "memory");

  for (int it = 0; it < 32; ++it) {
    const int cur = it % 3;
    if (it < 31) asm volatile("s_waitcnt vmcnt(12)" ::: "memory");
    else         asm volatile("s_waitcnt vmcnt(8)" ::: "memory");
    __builtin_amdgcn_s_barrier();
    __builtin_amdgcn_sched_barrier(0);
    if (it < 30) {
      const int nb = (it + 2) % 3;
      const int s_next = (it + 2) * 64;
      gload_lds16(kb + (size_t)(s_next + skey0) * CH + kc0, &KV[nb][(wave * 2) * 512]);
      gload_lds16(kb + (size_t)(s_next + skey1) * CH + kc1, &KV[nb][(wave * 2 + 1) * 512]);
      gload_lds16(vb + (size_t)skey0 * T_ + s_next + kc0, &KV[3 + nb][(wave * 2) * 512]);
      gload_lds16(vb + (size_t)skey1 * T_ + s_next + kc1, &KV[3 + nb][(wave * 2 + 1) * 512]);
    }
    if (it < 31) {
      const int s_next = (it + 1) * 64;
      #pragma unroll
      for (int j = 0; j < 4; ++j)
        mnext[j] = mbitsT[(size_t)(s_next >> 6) * T_ + qw0 + j * 16 + l15];
    }

    bf16x8 kf[4][2], vf[2][4];
    #pragma unroll
    for (int ni = 0; ni < 4; ++ni) {
      int row = ni * 16 + l15;
      kf[ni][0] = *(const bf16x8*)&KV[cur][row * 64 + ((l4 ^ (row & 7)) << 3)];
      kf[ni][1] = *(const bf16x8*)&KV[cur][row * 64 + (((4 + l4) ^ (row & 7)) << 3)];
    }
    #pragma unroll
    for (int j2 = 0; j2 < 2; ++j2)
      #pragma unroll
      for (int ci = 0; ci < 4; ++ci) {
        int row = ci * 16 + l15;
        vf[j2][ci] = *(const bf16x8*)&KV[3 + cur][row * 64 + (((j2 * 4 + l4) ^ (row & 7)) << 3)];
      }

    #pragma unroll
    for (int j = 0; j < 4; ++j) {
      f32x4 S[4];
      __builtin_amdgcn_s_setprio(1);
      #pragma unroll
      for (int ni = 0; ni < 4; ++ni) {
        f32x4 z = __builtin_amdgcn_mfma_f32_16x16x32_bf16(kf[ni][0], qa[j][0], zero, 0, 0, 0);
        S[ni] = __builtin_amdgcn_mfma_f32_16x16x32_bf16(kf[ni][1], qa[j][1], z, 0, 0, 0);
      }
      __builtin_amdgcn_s_setprio(0);
      unsigned long long mb = mcur[j];
      unsigned w0 = (unsigned)(mb >> (l4 * 4));
      unsigned w1 = (unsigned)(mb >> (l4 * 4 + 32));
      #pragma unroll
      for (int ni = 0; ni < 4; ++ni)
        #pragma unroll
        for (int r = 0; r < 4; ++r) {
          unsigned bit = ((ni < 2 ? (w0 >> (16 * ni + r)) : (w1 >> (16 * (ni - 2) + r))) & 1u);
          S[ni][r] = __builtin_amdgcn_exp2f(fminf(bit ? S[ni][r] : NINF, 24.f));
        }
      union { unsigned u[4]; bf16x8 v; } pf0, pf1;
      pf0.u[0] = cvt_pk_bf16(S[0][0], S[0][1]);
      pf0.u[1] = cvt_pk_bf16(S[0][2], S[0][3]);
      pf0.u[2] = cvt_pk_bf16(S[1][0], S[1][1]);
      pf0.u[3] = cvt_pk_bf16(S[1][2], S[1][3]);
      pf1.u[0] = cvt_pk_bf16(S[2][0], S[2][1]);
      pf1.u[1] = cvt_pk_bf16(S[2][2], S[2][3]);
      pf1.u[2] = cvt_pk_bf16(S[3][0], S[3][1]);
      pf1.u[3] = cvt_pk_bf16(S[3][2], S[3][3]);
      __builtin_amdgcn_s_setprio(1);
      lacc[j] = __builtin_amdgcn_mfma_f32_16x16x32_bf16(ones.v, pf0.v, lacc[j], 0, 0, 0);
      #pragma unroll
      for (int ci = 0; ci < 4; ++ci)
        O[j][ci] = __builtin_amdgcn_mfma_f32_16x16x32_bf16(vf[0][ci], pf0.v, O[j][ci], 0, 0, 0);
      lacc[j] = __builtin_amdgcn_mfma_f32_16x16x32_bf16(ones.v, pf1.v, lacc[j], 0, 0, 0);
      #pragma unroll
      for (int ci = 0; ci < 4; ++ci)
        O[j][ci] = __builtin_amdgcn_mfma_f32_16x16x32_bf16(vf[1][ci], pf1.v, O[j][ci], 0, 0, 0);
      __builtin_amdgcn_s_setprio(0);
      mcur[j] = mnext[j];
    }
  }

  __builtin_amdgcn_s_barrier();
  asm volatile("s_waitcnt vmcnt(0)" ::: "memory");
  __hip_bfloat16* scr = &KV[wave][0];
  #pragma unroll
  for (int j = 0; j < 4; ++j) {
    float invl = 1.f / lacc[j][0];
    int prow = j * 16 + l15;
    #pragma unroll
    for (int ci = 0; ci < 4; ++ci)
      #pragma unroll
      for (int pp = 0; pp < 2; ++pp) {
        int ch = ci * 16 + l4 * 4 + pp * 2;
        int chunk = ch >> 3, wi = ch & 7;
        unsigned pk = cvt_pk_bf16(O[j][ci][pp * 2] * invl, O[j][ci][pp * 2 + 1] * invl);
        *(unsigned*)&scr[prow * 64 + ((chunk ^ (prow & 7)) << 3) + wi] = pk;
      }
  }
  #pragma unroll
  for (int rd = 0; rd < 8; ++rd) {
    int row = rd * 8 + (lane >> 3);
    int chunk = lane & 7;
    bf16x8 ov = *(const bf16x8*)&scr[row * 64 + ((chunk ^ (row & 7)) << 3)];
    int t = qt * 256 + wave * 64 + row;
    *(bf16x8*)(at + ((size_t)b * T_ + t) * C_ + h * 64 + chunk * 8) = ov;
  }
}

extern "C" void kernel_launch(void* const* d_in, const int* in_sizes, int n_in,
                              void* d_out, int out_size, void* d_ws, size_t ws_size,
                              hipStream_t stream) {
  const float* x    = (const float*)d_in[0];
  const unsigned char* mask = (const unsigned char*)d_in[1];
  const float* gnw  = (const float*)d_in[2];
  const float* gnb  = (const float*)d_in[3];
  const float* Wqkv = (const float*)d_in[4];
  const float* bqkv = (const float*)d_in[5];
  const float* Wproj= (const float*)d_in[6];
  const float* bproj= (const float*)d_in[7];
  float* out = (float*)d_out;
  char* ws = (char*)d_ws;

  float* stats = (float*)ws;                                   // 1 KB
  int* mflag   = (int*)(ws + 1024);
  unsigned long long* mbits = (unsigned long long*)(ws + 4096); // [32][2048] u64 = 512 KB
  __hip_bfloat16* xnt = (__hip_bfloat16*)(ws + 4096 + 524288);  // [8192][1024]
  __hip_bfloat16* qb  = xnt + (size_t)NTOT * C_;               // [64][2048][64]
  __hip_bfloat16* kb  = qb  + (size_t)NBH * T_ * CH;
  __hip_bfloat16* vtb = kb  + (size_t)NBH * T_ * CH;           // [64][64][2048] (key-permuted)
  __hip_bfloat16* atb = vtb + (size_t)NBH * CH * T_;           // [8192][1024]
  __hip_bfloat16* wqb = atb + (size_t)NTOT * C_;               // [3072][1024]
  __hip_bfloat16* wpb = wqb + (size_t)3 * C_ * C_;             // [1024][1024]

  prep_a_kernel<<<4225, 256, 0, stream>>>(mask, mflag, x, stats, Wqkv, wqb, Wproj, wpb);
  prep_b_kernel<<<2304, 256, 0, stream>>>(mask, mflag, mbits, x, stats, gnw, gnb, xnt);
  gemm_bt_kernel<0><<<1536, 256, 0, stream>>>(wqb, xnt, bqkv, qb, kb, vtb,
      nullptr, nullptr, nullptr, nullptr, nullptr, C_, 24);
  attn_kernel<<<512, 256, 0, stream>>>(qb, kb, vtb, mbits, atb);
  gemm_bt_kernel<1><<<512, 256, 0, stream>>>(wpb, atb, bproj,
      nullptr, nullptr, nullptr, x, stats, gnw, gnb, out, C_, 8);
}